// Round 6
// baseline (126.890 us; speedup 1.0000x reference)
//
#include <hip/hip_runtime.h>
#include <hip/hip_bf16.h>
#include <cstddef>
#include <cstdint>

#define B_ 8
#define H_ 8
#define N_ 512
#define K_ 16
#define NN_ (N_*N_)

static constexpr float ALPHA_C = 0.001f;

typedef float f32x4 __attribute__((ext_vector_type(4)));

#define LDSTRIDE 20   // floats per LDS row: 16 + 4 pad, keeps 16B alignment

// -------------------------------------------------------------------------
// Strip matmul helpers (expm): one wave owns one 16x16 matrix.
//   lane -> row r = lane>>2, col strip c0 = 4*(lane&3).
// -------------------------------------------------------------------------
__device__ __forceinline__ void mm_rowB(const float* a, const float* Bbuf,
                                        int c0, f32x4& acc)
{
    #pragma unroll
    for (int k = 0; k < 16; ++k) {
        const f32x4 bk = *(const f32x4*)&Bbuf[k * LDSTRIDE + c0];
        acc.x = fmaf(a[k], bk.x, acc.x);
        acc.y = fmaf(a[k], bk.y, acc.y);
        acc.z = fmaf(a[k], bk.z, acc.z);
        acc.w = fmaf(a[k], bk.w, acc.w);
    }
}

__device__ __forceinline__ void read_row(const float* buf, int r, float* a)
{
    #pragma unroll
    for (int i = 0; i < 4; ++i) {
        const f32x4 t = *(const f32x4*)&buf[r * LDSTRIDE + 4 * i];
        a[4*i]   = t.x; a[4*i+1] = t.y; a[4*i+2] = t.z; a[4*i+3] = t.w;
    }
}

__device__ __forceinline__ void write_strip(float* buf, int r, int c0, f32x4 s)
{
    *(f32x4*)&buf[r * LDSTRIDE + c0] = s;
}

// -------------------------------------------------------------------------
// Kernel 1: per (b,n): beta head-mean for row n (PHASE 1, bt[] dies before
// phase 2 -> no pressure on the matmul chain), then Om = expm(phi.G)
// (scaling-and-squaring + degree-12 Taylor, 5 matmuls; verified round-1
// body). Barrierless. Emits Om, v = Om^T mu, q, bavg.
// (R5 version, UNCHANGED -- control arm of this round's A/B.)
// -------------------------------------------------------------------------
__global__ __launch_bounds__(256) void expm_beta_kernel(
    const float* __restrict__ mu, const float* __restrict__ phi,
    const float* __restrict__ gen, const float* __restrict__ beta,
    float* __restrict__ Om, float* __restrict__ v, float* __restrict__ q,
    float* __restrict__ bavg)
{
    __shared__ float lds[4][2][16 * LDSTRIDE];

    const int tid  = threadIdx.x;
    const int w    = tid >> 6, lane = tid & 63;
    const int r    = lane >> 2, c0 = (lane & 3) << 2;
    const int bn   = (blockIdx.x << 2) | w;
    const int bb   = bn >> 9;            // batch index
    const int nn   = bn & 511;           // row index

    float* U0 = lds[w][0];
    float* U1 = lds[w][1];

    // --- issue expm inputs ---
    const float p0 = phi[bn*3+0], p1 = phi[bn*3+1], p2 = phi[bn*3+2];
    const int gidx = r * 16 + c0;
    const f32x4 g0 = *(const f32x4*)&gen[gidx];
    const f32x4 g1 = *(const f32x4*)&gen[256 + gidx];
    const f32x4 g2 = *(const f32x4*)&gen[512 + gidx];
    const float mur = mu[bn * 16 + r];

    // --- issue the full beta burst (16 nontemporal loads, 1 KB/lane) ---
    const size_t betaBase = (((size_t)bb * H_) * N_ + nn) * N_;
    const float* bp = beta + betaBase + (lane << 2);
    f32x4 bt[16];
    #pragma unroll
    for (int h = 0; h < H_; ++h) {
        bt[2*h+0] = __builtin_nontemporal_load((const f32x4*)(bp + (size_t)h * NN_));
        bt[2*h+1] = __builtin_nontemporal_load((const f32x4*)(bp + (size_t)h * NN_ + 256));
    }

    // --- beta-independent prologue hides part of the burst latency ---
    f32x4 As;
    As.x = p0*g0.x + p1*g1.x + p2*g2.x;
    As.y = p0*g0.y + p1*g1.y + p2*g2.y;
    As.z = p0*g0.z + p1*g1.z + p2*g2.z;
    As.w = p0*g0.w + p1*g1.w + p2*g2.w;

    float t = As.x*As.x + As.y*As.y + As.z*As.z + As.w*As.w;
    #pragma unroll
    for (int m = 1; m <= 32; m <<= 1) t += __shfl_xor(t, m, 64);
    float theta = sqrtf(t);
    int s = 0;
    while (theta > 2.0f && s < 30) { theta *= 0.5f; ++s; }
    const float sc = exp2f((float)(-s));
    const f32x4 Xs = As * sc;

    write_strip(U0, r, c0, Xs);
    float xrow[16];
    read_row(U0, r, xrow);

    // --- fold beta NOW (bt dies here), store bavg (plain: re-read by k2) ---
    {
        const f32x4 rv0 = (((bt[0]+bt[2]) + (bt[4]+bt[6]))
                         + ((bt[8]+bt[10]) + (bt[12]+bt[14]))) * 0.125f;
        const f32x4 rv1 = (((bt[1]+bt[3]) + (bt[5]+bt[7]))
                         + ((bt[9]+bt[11]) + (bt[13]+bt[15]))) * 0.125f;
        float* bo = bavg + (size_t)bn * N_ + (lane << 2);
        *(f32x4*)bo         = rv0;
        *(f32x4*)(bo + 256) = rv1;
    }

    // --- phase 2: the verified expm chain (no beta registers live) ---
    f32x4 a2s = {0.f, 0.f, 0.f, 0.f};
    mm_rowB(xrow, U0, c0, a2s);
    write_strip(U1, r, c0, a2s);

    f32x4 a3s = {0.f, 0.f, 0.f, 0.f};
    mm_rowB(xrow, U1, c0, a3s);

    float a2row[16];
    read_row(U1, r, a2row);
    f32x4 a4s = {0.f, 0.f, 0.f, 0.f};
    mm_rowB(a2row, U1, c0, a4s);
    write_strip(U0, r, c0, a4s);
    float a4row[16];
    read_row(U0, r, a4row);

    f32x4 di = {0.f, 0.f, 0.f, 0.f};
    if (r >= c0 && r < c0 + 4) ((float*)&di)[r - c0] = 1.0f;

    const f32x4 C0 = di + Xs + a2s * 0.5f + a3s * (1.0f/6.0f);
    const f32x4 C1 = di * (1.0f/24.0f) + Xs * (1.0f/120.0f)
                   + a2s * (1.0f/720.0f) + a3s * (1.0f/5040.0f);
    const f32x4 Q2 = di * (1.0f/40320.0f) + Xs * (1.0f/362880.0f)
                   + a2s * (1.0f/3628800.0f) + a3s * (1.0f/39916800.0f)
                   + a4s * (1.0f/479001600.0f);

    write_strip(U1, r, c0, Q2);
    f32x4 T1 = C1;
    mm_rowB(a4row, U1, c0, T1);

    write_strip(U1, r, c0, T1);
    f32x4 P = C0;
    mm_rowB(a4row, U1, c0, P);

    for (int it = 0; it < s; ++it) {
        write_strip(U1, r, c0, P);
        float prow[16];
        read_row(U1, r, prow);
        f32x4 Pn = {0.f, 0.f, 0.f, 0.f};
        mm_rowB(prow, U1, c0, Pn);
        P = Pn;
    }

    *(f32x4*)&Om[(size_t)bn * 256 + r * 16 + c0] = P;

    f32x4 vc = P * mur;
    #pragma unroll
    for (int m = 4; m <= 32; m <<= 1) {
        vc.x += __shfl_xor(vc.x, m, 64);
        vc.y += __shfl_xor(vc.y, m, 64);
        vc.z += __shfl_xor(vc.z, m, 64);
        vc.w += __shfl_xor(vc.w, m, 64);
    }
    if (r == 0) *(f32x4*)&v[bn * 16 + c0] = vc;

    float qp = vc.x*vc.x + vc.y*vc.y + vc.z*vc.z + vc.w*vc.w;
    qp += __shfl_xor(qp, 1, 64);
    qp += __shfl_xor(qp, 2, 64);
    if (lane == 0) q[bn] = 0.5f * qp;
}

// -------------------------------------------------------------------------
// Reduction helpers for grad (register arrays, fully unrolled -> static idx).
// -------------------------------------------------------------------------
__device__ __forceinline__ float fold16(float* wc, int lane)
{
    #pragma unroll
    for (int k = 0; k < 8; ++k) {             // mask 32, keep 8
        const bool up = (lane & 32) != 0;
        const float send = up ? wc[k] : wc[k + 8];
        const float recv = __shfl_xor(send, 32, 64);
        wc[k] = (up ? wc[k + 8] : wc[k]) + recv;
    }
    #pragma unroll
    for (int k = 0; k < 4; ++k) {             // mask 16, keep 4
        const bool up = (lane & 16) != 0;
        const float send = up ? wc[k] : wc[k + 4];
        const float recv = __shfl_xor(send, 16, 64);
        wc[k] = (up ? wc[k + 4] : wc[k]) + recv;
    }
    #pragma unroll
    for (int k = 0; k < 2; ++k) {             // mask 8, keep 2
        const bool up = (lane & 8) != 0;
        const float send = up ? wc[k] : wc[k + 2];
        const float recv = __shfl_xor(send, 8, 64);
        wc[k] = (up ? wc[k + 2] : wc[k]) + recv;
    }
    {                                          // mask 4, keep 1
        const bool up = (lane & 4) != 0;
        const float send = up ? wc[0] : wc[1];
        const float recv = __shfl_xor(send, 4, 64);
        wc[0] = (up ? wc[1] : wc[0]) + recv;
    }
    wc[0] += __shfl_xor(wc[0], 2, 64);
    wc[0] += __shfl_xor(wc[0], 1, 64);
    return wc[0];
}

__device__ __forceinline__ float rot_reduce(const float* omr, float gv, int lane)
{
    float pr[4];
    #pragma unroll
    for (int rr = 0; rr < 4; ++rr) pr[rr] = omr[rr] * gv;

    #pragma unroll
    for (int k = 0; k < 2; ++k) {             // mask 4, keep 2
        const bool up = (lane & 4) != 0;
        const float send = up ? pr[k] : pr[k + 2];
        const float recv = __shfl_xor(send, 4, 64);
        pr[k] = (up ? pr[k + 2] : pr[k]) + recv;
    }
    {                                          // mask 8, keep 1
        const bool up = (lane & 8) != 0;
        const float send = up ? pr[0] : pr[1];
        const float recv = __shfl_xor(send, 8, 64);
        pr[0] = (up ? pr[1] : pr[0]) + recv;
    }
    pr[0] += __shfl_xor(pr[0], 16, 64);
    pr[0] += __shfl_xor(pr[0], 32, 64);
    return pr[0];
}

// -------------------------------------------------------------------------
// Kernel 2 (v6): ONE row per wave, 4 rows/block -> 1024 blocks, with the
// v5 combined-coefficient algebra:
//   wc[k] = sum_j (oms*rv_j + rkl_j) * vj[k]
// Rationale (R5 post-mortem): the 2-row design was grid-limited to 2
// blocks/CU = 2 waves/SIMD -- too few to hide the serial shuffle chains
// and staging barrier. 1-row halves per-wave register demand (~60 peak:
// tq 32 + rv 8 + addr at staging; wc 16 + c 8 in w-pass) ->
// __launch_bounds__(256,3): cap 84 (law: cap=256/arg), 3 blocks/CU,
// 12 waves/CU, LDS 3 x 35.3 KB = 106 KB <= 160. No spill margin risk.
// -------------------------------------------------------------------------
__global__ __launch_bounds__(256, 3) void grad_kernel(
    const float* __restrict__ mu, const float* __restrict__ mu_prior,
    const float* __restrict__ lrp, const float* __restrict__ Om,
    const float* __restrict__ v, const float* __restrict__ q,
    const float* __restrict__ bavg, float* __restrict__ out)
{
    __shared__ float v_t[16 * 516];      // 16 rows x 129 float4 (pad 1 f4)
    __shared__ f32x4 q4[128];

    const int blk = blockIdx.x;          // 0..1023
    const int b   = blk >> 7;
    const int i0  = (blk & 127) << 2;
    const int tid = threadIdx.x;
    const int wid = tid >> 6, lane = tid & 63;
    const int i   = i0 + wid;
    const size_t rowi = (size_t)b * N_ + i;

    // ---- 1. issue v staging + q + bavg ----
    const float* vb = v + (size_t)b * N_ * K_;
    f32x4 tq[8];
    #pragma unroll
    for (int s = 0; s < 8; ++s)
        tq[s] = *(const f32x4*)&vb[(tid + 256 * s) << 2];

    f32x4 qreg = {0.f, 0.f, 0.f, 0.f};
    const f32x4* qb4 = (const f32x4*)(q + (size_t)b * N_);
    if (tid < 128) qreg = qb4[tid];

    const float* bpr = bavg + rowi * N_ + (lane << 2);
    const f32x4 rv0 = *(const f32x4*)bpr;          // h-mean, j = 4*lane..
    const f32x4 rv1 = *(const f32x4*)(bpr + 256);  // j-half 2

    // ---- 2. LDS scatter of staged v (transposed) ----
    #pragma unroll
    for (int s = 0; s < 8; ++s) {
        const int f4 = tid + 256 * s;
        const int j  = f4 >> 2;
        const int k0 = (f4 & 3) << 2;
        v_t[(k0+0) * 516 + j] = tq[s].x;
        v_t[(k0+1) * 516 + j] = tq[s].y;
        v_t[(k0+2) * 516 + j] = tq[s].z;
        v_t[(k0+3) * 516 + j] = tq[s].w;
    }
    if (tid < 128) q4[tid] = qreg;
    __syncthreads();

    // ---- 3. vi broadcast reads; d-pass for both j-halves ----
    float vi[16];
    #pragma unroll
    for (int k = 0; k < 16; ++k) vi[k] = v_t[k * 516 + i];
    const float qi = ((const float*)q4)[i];

    const int j0 = lane << 2;

    float dA0 = 0.f, dA1 = 0.f, dA2 = 0.f, dA3 = 0.f;
    #pragma unroll
    for (int k = 0; k < 16; ++k) {
        const f32x4 vj = *(const f32x4*)&v_t[k * 516 + j0];
        dA0 = fmaf(vi[k], vj.x, dA0);
        dA1 = fmaf(vi[k], vj.y, dA1);
        dA2 = fmaf(vi[k], vj.z, dA2);
        dA3 = fmaf(vi[k], vj.w, dA3);
    }
    float dB0 = 0.f, dB1 = 0.f, dB2 = 0.f, dB3 = 0.f;
    #pragma unroll
    for (int k = 0; k < 16; ++k) {
        const f32x4 vj = *(const f32x4*)&v_t[k * 516 + j0 + 256];
        dB0 = fmaf(vi[k], vj.x, dB0);
        dB1 = fmaf(vi[k], vj.y, dB1);
        dB2 = fmaf(vi[k], vj.z, dB2);
        dB3 = fmaf(vi[k], vj.w, dB3);
    }

    // ---- 4. rkl for both halves ----
    const f32x4 qjA = q4[lane];
    const f32x4 qjB = q4[lane | 64];
    const float rklA0 = rv0.x * (qi + qjA.x - dA0);
    const float rklA1 = rv0.y * (qi + qjA.y - dA1);
    const float rklA2 = rv0.z * (qi + qjA.z - dA2);
    const float rklA3 = rv0.w * (qi + qjA.w - dA3);
    const float rklB0 = rv1.x * (qi + qjB.x - dB0);
    const float rklB1 = rv1.y * (qi + qjB.y - dB1);
    const float rklB2 = rv1.z * (qi + qjB.z - dB2);
    const float rklB3 = rv1.w * (qi + qjB.w - dB3);

    float sacc = ((rklA0 + rklA1) + (rklA2 + rklA3))
               + ((rklB0 + rklB1) + (rklB2 + rklB3));
    float R    = ((rv0.x + rv0.y) + (rv0.z + rv0.w))
               + ((rv1.x + rv1.y) + (rv1.z + rv1.w));

    // ---- 5. epilogue loads issued here; latency drains under butterfly ----
    const int cmine = (lane >> 2) & 15;
    const int tqi   = lane & 3;
    const float* omb = Om + rowi * 256;
    float omr[4];
    #pragma unroll
    for (int rr = 0; rr < 4; ++rr)
        omr[rr] = omb[(4 * tqi + rr) * 16 + cmine];

    const int row = 4 * tqi + 2 * ((lane >> 2) & 1) + ((lane >> 3) & 1);
    const size_t oi = rowi * 16 + row;
    float m0 = 0.f, mp = 0.f;
    if (lane < 16) { m0 = mu[oi]; mp = mu_prior[oi]; }
    const float lrv = lrp[0];

    // ---- 6. butterfly the two scalars (oms needed BEFORE w-pass) ----
    #pragma unroll
    for (int off = 32; off > 0; off >>= 1) {
        sacc += __shfl_xor(sacc, off, 64);
        R    += __shfl_xor(R,    off, 64);
    }
    const float oms  = 1.0f - sacc;
    const float coef = oms * R + sacc;

    // ---- 7. combined coefficients c = oms*rv + rkl ----
    const float cA0 = fmaf(oms, rv0.x, rklA0);
    const float cA1 = fmaf(oms, rv0.y, rklA1);
    const float cA2 = fmaf(oms, rv0.z, rklA2);
    const float cA3 = fmaf(oms, rv0.w, rklA3);
    const float cB0 = fmaf(oms, rv1.x, rklB0);
    const float cB1 = fmaf(oms, rv1.y, rklB1);
    const float cB2 = fmaf(oms, rv1.z, rklB2);
    const float cB3 = fmaf(oms, rv1.w, rklB3);

    // ---- 8. w-pass: single accumulator set, both halves ----
    float wc[16];
    #pragma unroll
    for (int k = 0; k < 16; ++k) wc[k] = 0.f;

    #pragma unroll
    for (int k = 0; k < 16; ++k) {
        const f32x4 vj = *(const f32x4*)&v_t[k * 516 + j0];
        float t1 = fmaf(cA0, vj.x, wc[k]);
        t1 = fmaf(cA1, vj.y, t1);
        t1 = fmaf(cA2, vj.z, t1);
        wc[k] = fmaf(cA3, vj.w, t1);
    }
    #pragma unroll
    for (int k = 0; k < 16; ++k) {
        const f32x4 vj = *(const f32x4*)&v_t[k * 516 + j0 + 256];
        float t1 = fmaf(cB0, vj.x, wc[k]);
        t1 = fmaf(cB1, vj.y, t1);
        t1 = fmaf(cB2, vj.z, t1);
        wc[k] = fmaf(cB3, vj.w, t1);
    }

    // ---- 9. fold + rotate + write ----
    const float wf = fold16(wc, lane);

    const float gv = coef * v_t[cmine * 516 + i] - wf;
    const float pr = rot_reduce(omr, gv, lane);

    if (lane < 16) {
        out[oi] = m0 - lrv * (ALPHA_C * (m0 - mp) + pr);
    }
}

// -------------------------------------------------------------------------
extern "C" void kernel_launch(void* const* d_in, const int* in_sizes, int n_in,
                              void* d_out, int out_size, void* d_ws, size_t ws_size,
                              hipStream_t stream)
{
    const float* mu   = (const float*)d_in[0];
    const float* beta = (const float*)d_in[1];
    const float* mup  = (const float*)d_in[2];
    const float* phi  = (const float*)d_in[3];
    const float* gen  = (const float*)d_in[4];
    const float* lr   = (const float*)d_in[5];
    float* out = (float*)d_out;

    float* Om   = (float*)d_ws;                     // 4096*256 floats = 4 MB
    float* v    = Om + (size_t)4096 * 256;          // 4096*16
    float* q    = v  + (size_t)4096 * 16;           // 4096
    float* bavg = q  + (size_t)4096;                // 8*512*512 = 8 MB

    expm_beta_kernel<<<B_ * N_ / 4, 256, 0, stream>>>(mu, phi, gen, beta, Om, v, q, bavg);
    grad_kernel<<<B_ * (N_ / 4), 256, 0, stream>>>(mu, mup, lr, Om, v, q, bavg, out);
}